// Round 11
// baseline (119.512 us; speedup 1.0000x reference)
//
#include <hip/hip_runtime.h>
#include <hip/hip_bf16.h>

typedef __bf16 bf16x8 __attribute__((ext_vector_type(8)));
typedef float f32x4 __attribute__((ext_vector_type(4)));

// ---- workspace layout (bytes). ----
#define OFF_GMAT   0x10000ULL    //   2 MB bf16 G[1024][1024]
#define OFF_XB     0x210000ULL   //   8 MB bf16 x  [4096][1024]
#define OFF_XBT    0xA10000ULL   //   8 MB bf16 x^T per batch [4][1024][1024]; reused as Qb
#define OFF_XF     0x1210000ULL  //   8 MB bf16 X'=G@X [4096][1024]; reused as Ob
#define OFF_WQT    0x1A10000ULL  //   2 MB bf16 Wq^T (WkT,WvT,WoT contiguous after)
#define OFF_WKT    0x1C10000ULL
#define OFF_WVT    0x1E10000ULL
#define OFF_WOT    0x2010000ULL
#define OFF_KB     0x2210000ULL  //   8 MB bf16 K [4096][1024]
#define OFF_VTB    0x2A10000ULL  //   8 MB bf16 V^T [1024 d_full][4096 b*t]

static __device__ __forceinline__ unsigned short f2bf(float f) {
  union { float f; unsigned int u; } v; v.f = f;
  unsigned int r = v.u + 0x7FFFu + ((v.u >> 16) & 1u);  // RNE
  return (unsigned short)(r >> 16);
}

// async global->LDS, 16B per lane; LDS dest is wave-uniform base + lane*16
static __device__ __forceinline__ void g2l16(const unsigned short* g, unsigned short* l) {
  __builtin_amdgcn_global_load_lds(
      (const __attribute__((address_space(1))) unsigned int*)g,
      (__attribute__((address_space(3))) unsigned int*)l, 16, 0, 0);
}

__constant__ float PRIMES_F[16] = {2.f, 3.f, 5.f, 7.f, 11.f, 13.f, 17.f, 19.f,
                                   23.f, 29.f, 31.f, 37.f, 41.f, 43.f, 47.f, 53.f};

// merged prep (vectorized): z<4 -> x batch z (cast xb + transpose xbT);
// z in [4,8) -> weight z-4 transpose; z==8 -> Gm via CLOSED-FORM spectral kernel:
//   1024*g[d] = 1 + q^512*(-1)^d + 2*Re[(z - z^512)/(1-z)],  z = q*e^{i*2*pi*d/1024}
__global__ __launch_bounds__(256) void k_prep(
    const float* __restrict__ x, const float* __restrict__ w0,
    const float* __restrict__ w1, const float* __restrict__ w2,
    const float* __restrict__ w3, const float* __restrict__ alpha_p,
    unsigned short* __restrict__ xb, unsigned short* __restrict__ xbT,
    unsigned short* __restrict__ Wout, unsigned short* __restrict__ Gm) {
  __shared__ float tile[32][33];
  const int z = blockIdx.z;
  const int r0 = blockIdx.y * 32, c0 = blockIdx.x * 32;
  if (z == 8) {
    const int tx = threadIdx.x & 31, ty = threadIdx.x >> 5;
    const float alpha = fmaxf(fabsf(alpha_p[0]), 1e-6f);
    const float q = __expf(-alpha * (1.f / 1024.f));
    const float q512 = __expf(-alpha * 0.5f);
    #pragma unroll
    for (int i = 0; i < 4; i++) {
      const int t = r0 + ty + 8 * i, s = c0 + tx;
      const int d = (t - s) & 1023;
      float s_, c_;
      __sincosf((float)d * (6.28318530717958647692f / 1024.f), &s_, &c_);
      const float sgn = (d & 1) ? -1.f : 1.f;           // (-1)^d
      const float Nr = q * c_ - q512 * sgn, Ni = q * s_;
      const float Wr = 1.f - q * c_, Wi = -q * s_;
      const float sum = (Nr * Wr + Ni * Wi) / (Wr * Wr + Wi * Wi);
      const float gd = (1.f + q512 * sgn + 2.f * sum) * (1.f / 1024.f);
      Gm[(long)t * 1024 + s] = f2bf(gd);
    }
    return;
  }
  const bool isX = z < 4;
  const float* in = isX ? (x + ((long)z << 20))
                        : (z == 4 ? w0 : z == 5 ? w1 : z == 6 ? w2 : w3);
  const long ooff = isX ? ((long)z << 20) : ((long)(z - 4) << 20);
  const int ty = threadIdx.x >> 3;        // row 0..31
  const int c4 = (threadIdx.x & 7) * 4;   // col 0,4,...,28
  float4 v = *(const float4*)(in + (long)(r0 + ty) * 1024 + c0 + c4);
  if (isX) {
    ushort4 o; o.x = f2bf(v.x); o.y = f2bf(v.y); o.z = f2bf(v.z); o.w = f2bf(v.w);
    *(ushort4*)(xb + ooff + (long)(r0 + ty) * 1024 + c0 + c4) = o;
  }
  tile[ty][c4 + 0] = v.x; tile[ty][c4 + 1] = v.y;
  tile[ty][c4 + 2] = v.z; tile[ty][c4 + 3] = v.w;
  __syncthreads();
  unsigned short* outT = isX ? xbT : Wout;
  ushort4 o;
  o.x = f2bf(tile[c4 + 0][ty]); o.y = f2bf(tile[c4 + 1][ty]);
  o.z = f2bf(tile[c4 + 2][ty]); o.w = f2bf(tile[c4 + 3][ty]);
  *(ushort4*)(outT + ooff + (long)(c0 + ty) * 1024 + r0 + c4) = o;
}

// ====== Single-buffered GEMM core: 128x128, BK=64, 4 waves, 32 KB LDS ======
// (m97 structure; at >=3 blocks/CU, TLP hides staging — dbuf proven neutral, R8)
#define GEMM_CORE_SB(A_, Bt_, NK, KTOF, ACC_)                                        \
  const int tid = threadIdx.x, l = tid & 63, wid = tid >> 6;                         \
  const int lr = l & 15, lg = l >> 4;                                                \
  const int wm = (wid >> 1) * 64, wn = (wid & 1) * 64;                               \
  const int scol = ((l & 7) ^ (l >> 3)) * 8;                                         \
  const unsigned short* Ag = A_ + (long)(m0 + wid * 32 + (l >> 3)) * 1024 + scol;    \
  const unsigned short* Bg = Bt_ + (long)(n0 + wid * 32 + (l >> 3)) * 1024 + scol;   \
  const int xk = (lr & 7) << 4;                                                      \
  const int co[2] = {(0 + lg * 16) ^ xk, (64 + lg * 16) ^ xk};                       \
  for (int t = 0; t < (NK); ++t) {                                                   \
    const int kt = KTOF(t);                                                          \
    __syncthreads();                                                                 \
    _Pragma("unroll")                                                                \
    for (int c = 0; c < 4; c++) {                                                    \
      g2l16(Ag + (long)c * 8192 + kt, &As[wid * 2048 + c * 512]);                    \
      g2l16(Bg + (long)c * 8192 + kt, &Bs[wid * 2048 + c * 512]);                    \
    }                                                                                \
    __syncthreads();                                                                 \
    const char* Ab = (const char*)&As[0];                                            \
    const char* Bb = (const char*)&Bs[0];                                            \
    _Pragma("unroll")                                                                \
    for (int ks = 0; ks < 2; ks++) {                                                 \
      bf16x8 af[4], bfr[4];                                                          \
      _Pragma("unroll")                                                              \
      for (int mf = 0; mf < 4; mf++)                                                 \
        af[mf] = *(const bf16x8*)(Ab + (wm + mf * 16 + lr) * 128 + co[ks]);          \
      _Pragma("unroll")                                                              \
      for (int nf = 0; nf < 4; nf++)                                                 \
        bfr[nf] = *(const bf16x8*)(Bb + (wn + nf * 16 + lr) * 128 + co[ks]);         \
      _Pragma("unroll")                                                              \
      for (int mf = 0; mf < 4; mf++)                                                 \
        _Pragma("unroll")                                                            \
        for (int nf = 0; nf < 4; nf++)                                               \
          ACC_[mf][nf] = __builtin_amdgcn_mfma_f32_16x16x32_bf16(af[mf], bfr[nf],    \
                                                                 ACC_[mf][nf], 0, 0, 0); \
    }                                                                                \
  }

#define KT_LIN(t) ((t) << 6)

// ---- k_fvF: BANDED filter GEMM only: X' = G @ X, band -> 6 circular k-tiles.
// 256 blocks, XCD-swizzled. M=1024 (t rows of G), N=4096 (b,c cols = xbT rows).
__global__ __launch_bounds__(256) void k_fvF(
    const unsigned short* __restrict__ Gm, const unsigned short* __restrict__ xbT,
    unsigned short* __restrict__ Xf) {
  __shared__ __align__(16) unsigned short As[128 * 64];
  __shared__ __align__(16) unsigned short Bs[128 * 64];
  const int inner = blockIdx.x;
  const int o = (inner & 7) * 32 + (inner >> 3);
  const int m0 = (o & 7) * 128, n0 = (o >> 3) * 128;
  const int ktbase = (m0 - 128) & 1023;
  f32x4 acc[4][4] = {};
#define KT_BAND(t) ((ktbase + ((t) << 6)) & 1023)
  GEMM_CORE_SB(Gm, xbT, 6, KT_BAND, acc)
#undef KT_BAND
  #pragma unroll
  for (int nf = 0; nf < 4; nf++) {
    const int n = n0 + wn + nf * 16 + lr;
    #pragma unroll
    for (int mf = 0; mf < 4; mf++) {
      const int mb = wm + mf * 16 + lg * 4;
      #pragma unroll
      for (int r = 0; r < 4; r++) {
        const int m = m0 + mb + r;
        // C[t=m][(b,c)=n] -> Xf[(b<<10)+t][c]
        Xf[(long)((n & ~1023) + m) * 1024 + (n & 1023)] = f2bf(acc[mf][nf][r]);
      }
    }
  }
}

// ---- k_qkv: ONE dispatch, 768 blocks = 3/CU (2 QK-proj + 1 V-proj per CU).
// bid<512: Q|K = X' @ [Wq|Wk]^T + bias (dual bf16 out). bid>=512: V^T = Wv^T X^T + bv.
__global__ __launch_bounds__(256) void k_qkv(
    const unsigned short* __restrict__ Xf, const unsigned short* __restrict__ WqkT,
    const float* __restrict__ bq, const float* __restrict__ bk,
    unsigned short* __restrict__ Qb, unsigned short* __restrict__ Kb,
    const unsigned short* __restrict__ WvT, const unsigned short* __restrict__ xb,
    const float* __restrict__ bv, unsigned short* __restrict__ Vtb) {
  __shared__ __align__(16) unsigned short As[128 * 64];
  __shared__ __align__(16) unsigned short Bs[128 * 64];
  const int bid = blockIdx.x;
  const bool isV = bid >= 512;
  int m0, n0;
  const unsigned short *A_, *Bt_;
  if (isV) {
    const int inner = bid - 512;
    const int o = (inner & 7) * 32 + (inner >> 3);
    m0 = (o & 7) * 128; n0 = (o >> 3) * 128;
    A_ = WvT; Bt_ = xb;
  } else {
    const int o = (bid & 7) * 64 + (bid >> 3);
    m0 = (o & 31) * 128; n0 = (o >> 5) * 128;
    A_ = Xf; Bt_ = WqkT;
  }
  f32x4 acc[4][4] = {};
  GEMM_CORE_SB(A_, Bt_, 16, KT_LIN, acc)
  #pragma unroll
  for (int nf = 0; nf < 4; nf++) {
    const int n = n0 + wn + nf * 16 + lr;
    float bb = 0.f;
    unsigned short* Cd = nullptr;
    if (!isV) {
      bb = (n < 1024) ? bq[n] : bk[n - 1024];
      Cd = (n < 1024) ? Qb : Kb;
    }
    #pragma unroll
    for (int mf = 0; mf < 4; mf++) {
      const int mb = wm + mf * 16 + lg * 4;
      #pragma unroll
      for (int r = 0; r < 4; r++) {
        const int m = m0 + mb + r;
        const float v = acc[mf][nf][r];
        if (isV) {
          Vtb[(long)m * 4096 + n] = f2bf(v + bv[m]);
        } else {
          Cd[(long)m * 1024 + (n & 1023)] = f2bf(v + bb);
        }
      }
    }
  }
}

// ---- k_gemmO: out = O @ Wo^T + bo, fp32. BM=64 x BN=128 -> 512 blocks; pipelined.
__global__ __launch_bounds__(256) void k_gemmO(
    const unsigned short* __restrict__ A, const unsigned short* __restrict__ Bt,
    const float* __restrict__ bias, float* __restrict__ C) {
  __shared__ __align__(16) unsigned short As[2][64 * 64];    // 16 KB
  __shared__ __align__(16) unsigned short Bs[2][128 * 64];   // 32 KB
  const int orig = (blockIdx.x & 7) * 64 + (blockIdx.x >> 3);
  const int m0 = (orig & 63) * 64, n0 = (orig >> 6) * 128;
  const int tid = threadIdx.x, l = tid & 63, wid = tid >> 6;
  const int lr = l & 15, lg = l >> 4;
  const int wm = (wid >> 1) * 32, wn = (wid & 1) * 64;
  const int scol = ((l & 7) ^ (l >> 3)) * 8;
  const unsigned short* Ag = A + (long)(m0 + wid * 16 + (l >> 3)) * 1024 + scol;
  const unsigned short* Bg = Bt + (long)(n0 + wid * 32 + (l >> 3)) * 1024 + scol;
  const int xk = (lr & 7) << 4;
  const int co[2] = {(0 + lg * 16) ^ xk, (64 + lg * 16) ^ xk};
  {
    #pragma unroll
    for (int c = 0; c < 2; c++) g2l16(Ag + (long)c * 8192, &As[0][wid * 1024 + c * 512]);
    #pragma unroll
    for (int c = 0; c < 4; c++) g2l16(Bg + (long)c * 8192, &Bs[0][wid * 2048 + c * 512]);
    Ag += 64; Bg += 64;
  }
  __syncthreads();
  f32x4 acc[2][4] = {};
  for (int t = 0; t < 16; ++t) {
    const int cur = t & 1;
    if (t < 15) {
      const int nxt = cur ^ 1;
      #pragma unroll
      for (int c = 0; c < 2; c++) g2l16(Ag + (long)c * 8192, &As[nxt][wid * 1024 + c * 512]);
      #pragma unroll
      for (int c = 0; c < 4; c++) g2l16(Bg + (long)c * 8192, &Bs[nxt][wid * 2048 + c * 512]);
      Ag += 64; Bg += 64;
      asm volatile("s_waitcnt vmcnt(6)" ::: "memory");
    } else {
      asm volatile("s_waitcnt vmcnt(0)" ::: "memory");
    }
    __builtin_amdgcn_s_barrier();
    __builtin_amdgcn_sched_barrier(0);
    const char* Ab = (const char*)&As[cur][0];
    const char* Bb = (const char*)&Bs[cur][0];
    #pragma unroll
    for (int ks = 0; ks < 2; ks++) {
      bf16x8 af[2], bfr[4];
      #pragma unroll
      for (int mf = 0; mf < 2; mf++)
        af[mf] = *(const bf16x8*)(Ab + (wm + mf * 16 + lr) * 128 + co[ks]);
      #pragma unroll
      for (int nf = 0; nf < 4; nf++)
        bfr[nf] = *(const bf16x8*)(Bb + (wn + nf * 16 + lr) * 128 + co[ks]);
      #pragma unroll
      for (int mf = 0; mf < 2; mf++)
        #pragma unroll
        for (int nf = 0; nf < 4; nf++)
          acc[mf][nf] = __builtin_amdgcn_mfma_f32_16x16x32_bf16(af[mf], bfr[nf], acc[mf][nf], 0, 0, 0);
    }
    __builtin_amdgcn_sched_barrier(0);
    __builtin_amdgcn_s_barrier();
  }
  #pragma unroll
  for (int nf = 0; nf < 4; nf++) {
    const int n = n0 + wn + nf * 16 + lr;
    const float bb = bias[n];
    #pragma unroll
    for (int mf = 0; mf < 2; mf++) {
      const int mb = m0 + wm + mf * 16 + lg * 4;
      #pragma unroll
      for (int r = 0; r < 4; r++)
        C[(long)(mb + r) * 1024 + n] = acc[mf][nf][r] + bb;
    }
  }
}

// ---- fused attention: 8 waves x 16 q-rows (512 thr), TRIPLE-buffered K/V staging
//      (1 barrier/iter, 2 tiles in flight), Q in regs, rank-2 bias, exp2-domain,
//      64 KB LDS, XCD-swizzled (K/V L2 reuse).
__global__ __launch_bounds__(512) void k_attn(
    const unsigned short* __restrict__ Qb, const unsigned short* __restrict__ Kb,
    const unsigned short* __restrict__ Vtb,
    const float* __restrict__ bias_scale_p, unsigned short* __restrict__ Ob) {
  __shared__ __align__(16) unsigned short Kbuf[3][4096];  // 24 KB
  __shared__ __align__(16) unsigned short Vbuf[3][4096];  // 24 KB
  __shared__ __align__(16) unsigned short Ps[8][16 * 64]; // 16 KB  (= 64 KB)
  // decode: bid = (hb%8) + 8*qt + 64*(hb/8); all qt of a given hb land on XCD hb%8
  const int bid = blockIdx.x;
  const int qt = (bid >> 3) & 7;
  const int hb = ((bid >> 6) << 3) | (bid & 7);
  const int h = hb & 15, b = hb >> 4;
  const int tid = threadIdx.x, l = tid & 63, wid = tid >> 6;  // wid 0..7
  const int lr = l & 15, lg = l >> 4;
  const int q0 = qt * 128;
  const float LOG2E = 1.44269504088896f;
  const float c10 = bias_scale_p[0] * 0.1f * LOG2E;
  const float k1 = 0.125f * LOG2E;
  const float fh = PRIMES_F[h] * 3.14159265358979323846f;
  const unsigned short* Vth = Vtb + (long)h * 64 * 4096 + b * 1024;
  const int xk = (lr & 7) << 4;
  const int co[2] = {(0 + lg * 16) ^ xk, (64 + lg * 16) ^ xk};
  const int scol = ((l & 7) ^ (l >> 3)) * 8;

  // staging: wave stages rows [wid*8, wid*8+8) of K and V tiles (1 g2l16 each)
  const unsigned short* kg = Kb + (long)(b * 1024 + wid * 8 + (l >> 3)) * 1024 + h * 64 + scol;
  const unsigned short* vg = Vth + (long)(wid * 8 + (l >> 3)) * 4096 + scol;
  unsigned short* kls = &Kbuf[0][0];
  unsigned short* vls = &Vbuf[0][0];
  #define STAGE_TO(BI) \
    { g2l16(kg, kls + (BI) * 4096 + wid * 512); \
      g2l16(vg, vls + (BI) * 4096 + wid * 512); \
      kg += 64 * 1024; vg += 64; }

  STAGE_TO(0);  // tile 0
  STAGE_TO(1);  // tile 1

  // Q fragments (loop-invariant): wave's 16 q-rows
  bf16x8 af[2];
  #pragma unroll
  for (int ks = 0; ks < 2; ks++)
    af[ks] = *(const bf16x8*)(
        &Qb[(long)(b * 1024 + q0 + wid * 16 + lr) * 1024 + h * 64 + ks * 32 + lg * 8]);

  // t-side sincos (rows this lane owns: q0 + wid*16 + lg*4 + r)
  float st2[4], ct2[4];
  #pragma unroll
  for (int r = 0; r < 4; r++) {
    float tt = (float)(q0 + wid * 16 + lg * 4 + r);
    float s_, c_;
    __sincosf(fh * tt * (1.f / 1024.f), &s_, &c_);
    st2[r] = c10 * s_;
    ct2[r] = c10 * c_;
  }
  // s-side sincos: init at s = nf*16 + lr, rotate by fh*64/1024 per iter
  float ss4[4], cs4[4], sd, cd;
  __sincosf(fh * (1.f / 16.f), &sd, &cd);
  #pragma unroll
  for (int nf = 0; nf < 4; nf++)
    __sincosf(fh * (float)(nf * 16 + lr) * (1.f / 1024.f), &ss4[nf], &cs4[nf]);

  f32x4 acc_o[4] = {};
  float pden[4] = {};
  int cur = 0, stg = 2;
  __syncthreads();  // drains prologue stages (0,1) + Q loads

  for (int it = 0; it < 16; ++it) {
    if (it < 15) {
      asm volatile("s_waitcnt vmcnt(2)" ::: "memory");  // stage(it) complete
    } else {
      asm volatile("s_waitcnt vmcnt(0)" ::: "memory");
    }
    __builtin_amdgcn_s_barrier();   // all waves' stage(it) visible; buf[stg] free
    __builtin_amdgcn_sched_barrier(0);
    if (it < 14) { STAGE_TO(stg); } // tile it+2 -> buf[(it+2)%3]
    const char* Kbb = (const char*)kls + cur * 8192;
    const char* Vbb = (const char*)vls + cur * 8192;
    // S = Q K^T (wave's 16 q-rows x 64 s)
    f32x4 accs[4] = {};
    #pragma unroll
    for (int ks = 0; ks < 2; ks++) {
      bf16x8 bfr[4];
      #pragma unroll
      for (int nf = 0; nf < 4; nf++)
        bfr[nf] = *(const bf16x8*)(Kbb + (nf * 16 + lr) * 128 + co[ks]);
      __builtin_amdgcn_s_setprio(1);
      #pragma unroll
      for (int nf = 0; nf < 4; nf++)
        accs[nf] = __builtin_amdgcn_mfma_f32_16x16x32_bf16(af[ks], bfr[nf], accs[nf], 0, 0, 0);
      __builtin_amdgcn_s_setprio(0);
    }
    // P = exp2(S*k1 + st2*cos_s - ct2*sin_s); partials; P -> LDS (swizzled bf16)
    char* Pw = (char*)&Ps[wid][0];
    #pragma unroll
    for (int nf = 0; nf < 4; nf++) {
      #pragma unroll
      for (int r = 0; r < 4; r++) {
        float v = fmaf(accs[nf][r], k1, fmaf(st2[r], cs4[nf], -ct2[r] * ss4[nf]));
        float p;
        asm("v_exp_f32 %0, %1" : "=v"(p) : "v"(v));
        pden[r] += p;
        union { float f; unsigned int u; } pu; pu.f = p;
        const int prow = lg * 4 + r;
        *(unsigned short*)(Pw + prow * 128 + ((nf * 32 + lr * 2) ^ ((prow & 7) << 4))) =
            (unsigned short)((pu.u + 0x8000u) >> 16);
      }
    }
    // O += P @ V
    #pragma unroll
    for (int ks = 0; ks < 2; ks++) {
      bf16x8 pa = *(const bf16x8*)(Pw + lr * 128 + co[ks]);
      bf16x8 vb[4];
      #pragma unroll
      for (int nf = 0; nf < 4; nf++)
        vb[nf] = *(const bf16x8*)(Vbb + (nf * 16 + lr) * 128 + co[ks]);
      __builtin_amdgcn_s_setprio(1);
      #pragma unroll
      for (int nf = 0; nf < 4; nf++)
        acc_o[nf] = __builtin_amdgcn_mfma_f32_16x16x32_bf16(pa, vb[nf], acc_o[nf], 0, 0, 0);
      __builtin_amdgcn_s_setprio(0);
    }
    // rotate s-side sincos (s += 64) and buffer indices
    #pragma unroll
    for (int nf = 0; nf < 4; nf++) {
      float c_ = cs4[nf] * cd - ss4[nf] * sd;
      ss4[nf] = ss4[nf] * cd + cs4[nf] * sd;
      cs4[nf] = c_;
    }
    cur = (cur == 2) ? 0 : cur + 1;
    stg = (stg == 2) ? 0 : stg + 1;
  }
  #undef STAGE_TO
  // finish den: reduce across the 16 lanes of each row-group
  #pragma unroll
  for (int r = 0; r < 4; r++) {
    float dsum = pden[r];
    #pragma unroll
    for (int off = 1; off < 16; off <<= 1) dsum += __shfl_xor(dsum, off, 64);
    pden[r] = 1.0f / dsum;
  }
  const int tg = q0 + wid * 16 + lg * 4;
  #pragma unroll
  for (int nf = 0; nf < 4; nf++) {
    const int dd = nf * 16 + lr;
    #pragma unroll
    for (int r = 0; r < 4; r++) {
      float val = acc_o[nf][r] * pden[r];
      Ob[(long)(b * 1024 + tg + r) * 1024 + h * 64 + dd] = f2bf(val);
    }
  }
}

extern "C" void kernel_launch(void* const* d_in, const int* in_sizes, int n_in,
                              void* d_out, int out_size, void* d_ws, size_t ws_size,
                              hipStream_t stream) {
  const float* x   = (const float*)d_in[0];
  const float* Wq  = (const float*)d_in[1];
  const float* bq  = (const float*)d_in[2];
  const float* Wk  = (const float*)d_in[3];
  const float* bk  = (const float*)d_in[4];
  const float* Wv  = (const float*)d_in[5];
  const float* bv  = (const float*)d_in[6];
  const float* Wo  = (const float*)d_in[7];
  const float* bo  = (const float*)d_in[8];
  const float* bsc = (const float*)d_in[10];
  const float* alp = (const float*)d_in[11];
  char* ws = (char*)d_ws;
  unsigned short* Gm  = (unsigned short*)(ws + OFF_GMAT);
  unsigned short* xb  = (unsigned short*)(ws + OFF_XB);
  unsigned short* xbT = (unsigned short*)(ws + OFF_XBT);
  unsigned short* Xf  = (unsigned short*)(ws + OFF_XF);
  unsigned short* WqT = (unsigned short*)(ws + OFF_WQT);
  unsigned short* WvT = (unsigned short*)(ws + OFF_WVT);
  unsigned short* WoT = (unsigned short*)(ws + OFF_WOT);
  unsigned short* Qb  = xbT;  // alias: xbT dead after k_fvF (its last reader)
  unsigned short* Kb  = (unsigned short*)(ws + OFF_KB);
  unsigned short* Vtb = (unsigned short*)(ws + OFF_VTB);
  unsigned short* Ob  = Xf;   // alias: Xf dead after QK projection

  // prep: x cast+transpose, 4 weight transposes, Gm via closed-form g (z=8)
  k_prep<<<dim3(32, 32, 9), 256, 0, stream>>>(x, Wq, Wk, Wv, Wo, alp, xb, xbT, WqT, Gm);
  // X' = G @ X (banded circulant), 256 blocks, short
  k_fvF<<<256, 256, 0, stream>>>(Gm, xbT, Xf);
  // Q|K = X' [Wq|Wk]^T + bias  AND  V^T = Wv^T X^T + bv: 768 blocks = 3/CU
  k_qkv<<<768, 256, 0, stream>>>(Xf, WqT, bq, bk, Qb, Kb, WvT, xb, bv, Vtb);
  k_attn<<<512, 512, 0, stream>>>(Qb, Kb, Vtb, bsc, Ob);
  // out = O Wo + bo (fp32)
  k_gemmO<<<512, 256, 0, stream>>>(Ob, WoT, bo, (float*)d_out);
}

// Round 12
// 117.605 us; speedup vs baseline: 1.0162x; 1.0162x over previous
//
#include <hip/hip_runtime.h>
#include <hip/hip_bf16.h>

typedef __bf16 bf16x8 __attribute__((ext_vector_type(8)));
typedef float f32x4 __attribute__((ext_vector_type(4)));

// ---- workspace layout (bytes). ----
#define OFF_GMAT   0x10000ULL    //   2 MB bf16 G[1024][1024]
#define OFF_XB     0x210000ULL   //   8 MB bf16 x  [4096][1024]
#define OFF_XBT    0xA10000ULL   //   8 MB bf16 x^T per batch [4][1024][1024]; reused as Qb
#define OFF_XF     0x1210000ULL  //   8 MB bf16 X'=G@X [4096][1024]; reused as Ob
#define OFF_WQT    0x1A10000ULL  //   2 MB bf16 Wq^T (WkT,WvT,WoT contiguous after)
#define OFF_WKT    0x1C10000ULL
#define OFF_WVT    0x1E10000ULL
#define OFF_WOT    0x2010000ULL
#define OFF_KB     0x2210000ULL  //   8 MB bf16 K [4096][1024]
#define OFF_VTB    0x2A10000ULL  //   8 MB bf16 V^T [1024 d_full][4096 b*t]

static __device__ __forceinline__ unsigned short f2bf(float f) {
  union { float f; unsigned int u; } v; v.f = f;
  unsigned int r = v.u + 0x7FFFu + ((v.u >> 16) & 1u);  // RNE
  return (unsigned short)(r >> 16);
}

// async global->LDS, 16B per lane; LDS dest is wave-uniform base + lane*16
static __device__ __forceinline__ void g2l16(const unsigned short* g, unsigned short* l) {
  __builtin_amdgcn_global_load_lds(
      (const __attribute__((address_space(1))) unsigned int*)g,
      (__attribute__((address_space(3))) unsigned int*)l, 16, 0, 0);
}

__constant__ float PRIMES_F[16] = {2.f, 3.f, 5.f, 7.f, 11.f, 13.f, 17.f, 19.f,
                                   23.f, 29.f, 31.f, 37.f, 41.f, 43.f, 47.f, 53.f};

// merged prep (vectorized): z<4 -> x batch z (cast xb + transpose xbT);
// z in [4,8) -> weight z-4 transpose; z==8 -> Gm via CLOSED-FORM spectral kernel:
//   1024*g[d] = 1 + q^512*(-1)^d + 2*Re[(z - z^512)/(1-z)],  z = q*e^{i*2*pi*d/1024}
__global__ __launch_bounds__(256) void k_prep(
    const float* __restrict__ x, const float* __restrict__ w0,
    const float* __restrict__ w1, const float* __restrict__ w2,
    const float* __restrict__ w3, const float* __restrict__ alpha_p,
    unsigned short* __restrict__ xb, unsigned short* __restrict__ xbT,
    unsigned short* __restrict__ Wout, unsigned short* __restrict__ Gm) {
  __shared__ float tile[32][33];
  const int z = blockIdx.z;
  const int r0 = blockIdx.y * 32, c0 = blockIdx.x * 32;
  if (z == 8) {
    const int tx = threadIdx.x & 31, ty = threadIdx.x >> 5;
    const float alpha = fmaxf(fabsf(alpha_p[0]), 1e-6f);
    const float q = __expf(-alpha * (1.f / 1024.f));
    const float q512 = __expf(-alpha * 0.5f);
    #pragma unroll
    for (int i = 0; i < 4; i++) {
      const int t = r0 + ty + 8 * i, s = c0 + tx;
      const int d = (t - s) & 1023;
      float s_, c_;
      __sincosf((float)d * (6.28318530717958647692f / 1024.f), &s_, &c_);
      const float sgn = (d & 1) ? -1.f : 1.f;           // (-1)^d
      const float Nr = q * c_ - q512 * sgn, Ni = q * s_;
      const float Wr = 1.f - q * c_, Wi = -q * s_;
      const float sum = (Nr * Wr + Ni * Wi) / (Wr * Wr + Wi * Wi);
      const float gd = (1.f + q512 * sgn + 2.f * sum) * (1.f / 1024.f);
      Gm[(long)t * 1024 + s] = f2bf(gd);
    }
    return;
  }
  const bool isX = z < 4;
  const float* in = isX ? (x + ((long)z << 20))
                        : (z == 4 ? w0 : z == 5 ? w1 : z == 6 ? w2 : w3);
  const long ooff = isX ? ((long)z << 20) : ((long)(z - 4) << 20);
  const int ty = threadIdx.x >> 3;        // row 0..31
  const int c4 = (threadIdx.x & 7) * 4;   // col 0,4,...,28
  float4 v = *(const float4*)(in + (long)(r0 + ty) * 1024 + c0 + c4);
  if (isX) {
    ushort4 o; o.x = f2bf(v.x); o.y = f2bf(v.y); o.z = f2bf(v.z); o.w = f2bf(v.w);
    *(ushort4*)(xb + ooff + (long)(r0 + ty) * 1024 + c0 + c4) = o;
  }
  tile[ty][c4 + 0] = v.x; tile[ty][c4 + 1] = v.y;
  tile[ty][c4 + 2] = v.z; tile[ty][c4 + 3] = v.w;
  __syncthreads();
  unsigned short* outT = isX ? xbT : Wout;
  ushort4 o;
  o.x = f2bf(tile[c4 + 0][ty]); o.y = f2bf(tile[c4 + 1][ty]);
  o.z = f2bf(tile[c4 + 2][ty]); o.w = f2bf(tile[c4 + 3][ty]);
  *(ushort4*)(outT + ooff + (long)(c0 + ty) * 1024 + r0 + c4) = o;
}

// ====== GEMM core: 128x128, BK=64, 4 waves; PIPELINED (dbuf + counted vmcnt) ======
#define GEMM_CORE(A_, Bt_, ACC_)                                                     \
  const int tid = threadIdx.x, l = tid & 63, wid = tid >> 6;                         \
  const int lr = l & 15, lg = l >> 4;                                                \
  const int wm = (wid >> 1) * 64, wn = (wid & 1) * 64;                               \
  const int scol = ((l & 7) ^ (l >> 3)) * 8;                                         \
  const unsigned short* Ag = A_ + (long)(m0 + wid * 32 + (l >> 3)) * 1024 + scol;    \
  const unsigned short* Bg = Bt_ + (long)(n0 + wid * 32 + (l >> 3)) * 1024 + scol;   \
  const int xk = (lr & 7) << 4;                                                      \
  const int co[2] = {(0 + lg * 16) ^ xk, (64 + lg * 16) ^ xk};                       \
  {                                                                                  \
    _Pragma("unroll")                                                                \
    for (int c = 0; c < 4; c++) {                                                    \
      g2l16(Ag + (long)c * 8192, &As[0][wid * 2048 + c * 512]);                      \
      g2l16(Bg + (long)c * 8192, &Bs[0][wid * 2048 + c * 512]);                      \
    }                                                                                \
    Ag += 64; Bg += 64;                                                              \
  }                                                                                  \
  __syncthreads();                                                                   \
  for (int t = 0; t < 16; ++t) {                                                     \
    const int cur = t & 1;                                                           \
    if (t < 15) {                                                                    \
      const int nxt = cur ^ 1;                                                       \
      _Pragma("unroll")                                                              \
      for (int c = 0; c < 4; c++) {                                                  \
        g2l16(Ag + (long)c * 8192, &As[nxt][wid * 2048 + c * 512]);                  \
        g2l16(Bg + (long)c * 8192, &Bs[nxt][wid * 2048 + c * 512]);                  \
      }                                                                              \
      Ag += 64; Bg += 64;                                                            \
      asm volatile("s_waitcnt vmcnt(8)" ::: "memory");                               \
    } else {                                                                         \
      asm volatile("s_waitcnt vmcnt(0)" ::: "memory");                               \
    }                                                                                \
    __builtin_amdgcn_s_barrier();                                                    \
    __builtin_amdgcn_sched_barrier(0);                                               \
    const char* Ab = (const char*)&As[cur][0];                                       \
    const char* Bb = (const char*)&Bs[cur][0];                                       \
    _Pragma("unroll")                                                                \
    for (int ks = 0; ks < 2; ks++) {                                                 \
      bf16x8 af[4], bfr[4];                                                          \
      _Pragma("unroll")                                                              \
      for (int mf = 0; mf < 4; mf++)                                                 \
        af[mf] = *(const bf16x8*)(Ab + (wm + mf * 16 + lr) * 128 + co[ks]);          \
      _Pragma("unroll")                                                              \
      for (int nf = 0; nf < 4; nf++)                                                 \
        bfr[nf] = *(const bf16x8*)(Bb + (wn + nf * 16 + lr) * 128 + co[ks]);         \
      _Pragma("unroll")                                                              \
      for (int mf = 0; mf < 4; mf++)                                                 \
        _Pragma("unroll")                                                            \
        for (int nf = 0; nf < 4; nf++)                                               \
          ACC_[mf][nf] = __builtin_amdgcn_mfma_f32_16x16x32_bf16(af[mf], bfr[nf],    \
                                                                 ACC_[mf][nf], 0, 0, 0); \
    }                                                                                \
    __builtin_amdgcn_sched_barrier(0);                                               \
    __builtin_amdgcn_s_barrier();                                                    \
  }

// ---- k_gemm5: dual bf16 out (Q|K projection), M=4096, N=2048, grid 512, XCD-swizzled
__global__ __launch_bounds__(256) void k_gemm5(
    const unsigned short* __restrict__ A, const unsigned short* __restrict__ Bt,
    const float* __restrict__ bias, const float* __restrict__ bias2,
    unsigned short* __restrict__ Cv, unsigned short* __restrict__ Cv2) {
  __shared__ __align__(16) unsigned short As[2][128 * 64];
  __shared__ __align__(16) unsigned short Bs[2][128 * 64];
  const int orig = (blockIdx.x & 7) * 64 + (blockIdx.x >> 3);
  const int m0 = (orig & 31) * 128, n0 = (orig >> 5) * 128;
  f32x4 acc[4][4] = {};
  GEMM_CORE(A, Bt, acc)
  #pragma unroll
  for (int nf = 0; nf < 4; nf++) {
    const int n = n0 + wn + nf * 16 + lr;
    const float bb = (n < 1024) ? bias[n] : bias2[n - 1024];
    unsigned short* Cd = (n < 1024) ? Cv : Cv2;
    #pragma unroll
    for (int mf = 0; mf < 4; mf++) {
      const int mb = m0 + wm + mf * 16 + lg * 4;
      #pragma unroll
      for (int r = 0; r < 4; r++)
        Cd[(long)(mb + r) * 1024 + (n & 1023)] = f2bf(acc[mf][nf][r] + bb);
    }
  }
}

// ---- k_fv: dense V GEMM (bid 0..255, 16 kt) + BANDED filter GEMM (bid 256..511,
// band |t-s|<=64 -> 4 circular k-tiles). Balanced: each CU gets one V + one filter
// block (20 kt total). XCD swizzle within each half.
__global__ __launch_bounds__(256) void k_fv(
    const unsigned short* __restrict__ Gm, const unsigned short* __restrict__ xbT,
    const unsigned short* __restrict__ WvT, const unsigned short* __restrict__ xb,
    const float* __restrict__ bv, unsigned short* __restrict__ Xf,
    unsigned short* __restrict__ Vtb) {
  __shared__ __align__(16) unsigned short As[2][128 * 64];
  __shared__ __align__(16) unsigned short Bs[2][128 * 64];
  const bool isV = blockIdx.x < 256;
  const int inner = blockIdx.x & 255;
  const int o = (inner & 7) * 32 + (inner >> 3);  // XCD swizzle within half
  const int m0 = (o & 7) * 128, n0 = (o >> 3) * 128;
  const unsigned short* A_ = isV ? WvT : Gm;
  const unsigned short* Bt_ = isV ? xb : xbT;
  const int nk = isV ? 16 : 4;                     // banded filter: 4 k-tiles
  const int ktbase = isV ? 0 : ((m0 - 64) & 1023); // circular band start (+-64)
  const int tid = threadIdx.x, l = tid & 63, wid = tid >> 6;
  const int lr = l & 15, lg = l >> 4;
  const int wm = (wid >> 1) * 64, wn = (wid & 1) * 64;
  const int scol = ((l & 7) ^ (l >> 3)) * 8;
  const unsigned short* Ag = A_ + (long)(m0 + wid * 32 + (l >> 3)) * 1024 + scol;
  const unsigned short* Bg = Bt_ + (long)(n0 + wid * 32 + (l >> 3)) * 1024 + scol;
  const int xk = (lr & 7) << 4;
  const int co[2] = {(0 + lg * 16) ^ xk, (64 + lg * 16) ^ xk};
  {
    #pragma unroll
    for (int c = 0; c < 4; c++) {
      g2l16(Ag + (long)c * 8192 + ktbase, &As[0][wid * 2048 + c * 512]);
      g2l16(Bg + (long)c * 8192 + ktbase, &Bs[0][wid * 2048 + c * 512]);
    }
  }
  __syncthreads();
  f32x4 acc[4][4] = {};
  for (int t = 0; t < nk; ++t) {
    const int cur = t & 1;
    if (t < nk - 1) {
      const int nxt = cur ^ 1;
      const int kt = (ktbase + ((t + 1) << 6)) & 1023;
      #pragma unroll
      for (int c = 0; c < 4; c++) {
        g2l16(Ag + (long)c * 8192 + kt, &As[nxt][wid * 2048 + c * 512]);
        g2l16(Bg + (long)c * 8192 + kt, &Bs[nxt][wid * 2048 + c * 512]);
      }
      asm volatile("s_waitcnt vmcnt(8)" ::: "memory");
    } else {
      asm volatile("s_waitcnt vmcnt(0)" ::: "memory");
    }
    __builtin_amdgcn_s_barrier();
    __builtin_amdgcn_sched_barrier(0);
    const char* Ab = (const char*)&As[cur][0];
    const char* Bb = (const char*)&Bs[cur][0];
    #pragma unroll
    for (int ks = 0; ks < 2; ks++) {
      bf16x8 af[4], bfr[4];
      #pragma unroll
      for (int mf = 0; mf < 4; mf++)
        af[mf] = *(const bf16x8*)(Ab + (wm + mf * 16 + lr) * 128 + co[ks]);
      #pragma unroll
      for (int nf = 0; nf < 4; nf++)
        bfr[nf] = *(const bf16x8*)(Bb + (wn + nf * 16 + lr) * 128 + co[ks]);
      #pragma unroll
      for (int mf = 0; mf < 4; mf++)
        #pragma unroll
        for (int nf = 0; nf < 4; nf++)
          acc[mf][nf] = __builtin_amdgcn_mfma_f32_16x16x32_bf16(af[mf], bfr[nf], acc[mf][nf], 0, 0, 0);
    }
    __builtin_amdgcn_sched_barrier(0);
    __builtin_amdgcn_s_barrier();
  }
  #pragma unroll
  for (int nf = 0; nf < 4; nf++) {
    const int n = n0 + wn + nf * 16 + lr;
    #pragma unroll
    for (int mf = 0; mf < 4; mf++) {
      const int mb = wm + mf * 16 + lg * 4;
      #pragma unroll
      for (int r = 0; r < 4; r++) {
        const int m = m0 + mb + r;
        float v = acc[mf][nf][r];
        if (isV) {
          Vtb[(long)m * 4096 + n] = f2bf(v + bv[m]);
        } else {
          Xf[(long)((n & ~1023) + m) * 1024 + (n & 1023)] = f2bf(v);
        }
      }
    }
  }
}

// ---- k_gemmO: out = O @ Wo^T + bo, fp32. BM=64 x BN=128 -> 512 blocks; pipelined.
__global__ __launch_bounds__(256) void k_gemmO(
    const unsigned short* __restrict__ A, const unsigned short* __restrict__ Bt,
    const float* __restrict__ bias, float* __restrict__ C) {
  __shared__ __align__(16) unsigned short As[2][64 * 64];    // 16 KB
  __shared__ __align__(16) unsigned short Bs[2][128 * 64];   // 32 KB
  const int orig = (blockIdx.x & 7) * 64 + (blockIdx.x >> 3);
  const int m0 = (orig & 63) * 64, n0 = (orig >> 6) * 128;
  const int tid = threadIdx.x, l = tid & 63, wid = tid >> 6;
  const int lr = l & 15, lg = l >> 4;
  const int wm = (wid >> 1) * 32, wn = (wid & 1) * 64;
  const int scol = ((l & 7) ^ (l >> 3)) * 8;
  const unsigned short* Ag = A + (long)(m0 + wid * 16 + (l >> 3)) * 1024 + scol;
  const unsigned short* Bg = Bt + (long)(n0 + wid * 32 + (l >> 3)) * 1024 + scol;
  const int xk = (lr & 7) << 4;
  const int co[2] = {(0 + lg * 16) ^ xk, (64 + lg * 16) ^ xk};
  {
    #pragma unroll
    for (int c = 0; c < 2; c++) g2l16(Ag + (long)c * 8192, &As[0][wid * 1024 + c * 512]);
    #pragma unroll
    for (int c = 0; c < 4; c++) g2l16(Bg + (long)c * 8192, &Bs[0][wid * 2048 + c * 512]);
    Ag += 64; Bg += 64;
  }
  __syncthreads();
  f32x4 acc[2][4] = {};
  for (int t = 0; t < 16; ++t) {
    const int cur = t & 1;
    if (t < 15) {
      const int nxt = cur ^ 1;
      #pragma unroll
      for (int c = 0; c < 2; c++) g2l16(Ag + (long)c * 8192, &As[nxt][wid * 1024 + c * 512]);
      #pragma unroll
      for (int c = 0; c < 4; c++) g2l16(Bg + (long)c * 8192, &Bs[nxt][wid * 2048 + c * 512]);
      Ag += 64; Bg += 64;
      asm volatile("s_waitcnt vmcnt(6)" ::: "memory");
    } else {
      asm volatile("s_waitcnt vmcnt(0)" ::: "memory");
    }
    __builtin_amdgcn_s_barrier();
    __builtin_amdgcn_sched_barrier(0);
    const char* Ab = (const char*)&As[cur][0];
    const char* Bb = (const char*)&Bs[cur][0];
    #pragma unroll
    for (int ks = 0; ks < 2; ks++) {
      bf16x8 af[2], bfr[4];
      #pragma unroll
      for (int mf = 0; mf < 2; mf++)
        af[mf] = *(const bf16x8*)(Ab + (wm + mf * 16 + lr) * 128 + co[ks]);
      #pragma unroll
      for (int nf = 0; nf < 4; nf++)
        bfr[nf] = *(const bf16x8*)(Bb + (wn + nf * 16 + lr) * 128 + co[ks]);
      #pragma unroll
      for (int mf = 0; mf < 2; mf++)
        #pragma unroll
        for (int nf = 0; nf < 4; nf++)
          acc[mf][nf] = __builtin_amdgcn_mfma_f32_16x16x32_bf16(af[mf], bfr[nf], acc[mf][nf], 0, 0, 0);
    }
    __builtin_amdgcn_sched_barrier(0);
    __builtin_amdgcn_s_barrier();
  }
  #pragma unroll
  for (int nf = 0; nf < 4; nf++) {
    const int n = n0 + wn + nf * 16 + lr;
    const float bb = bias[n];
    #pragma unroll
    for (int mf = 0; mf < 2; mf++) {
      const int mb = m0 + wm + mf * 16 + lg * 4;
      #pragma unroll
      for (int r = 0; r < 4; r++)
        C[(long)(mb + r) * 1024 + n] = acc[mf][nf][r] + bb;
    }
  }
}

// ---- fused attention: 8 waves x 16 q-rows (512 thr), TRIPLE-buffered K/V staging
//      (1 barrier/iter, 2 tiles in flight), Q in regs, rank-2 bias, exp2-domain,
//      64 KB LDS, XCD-swizzled (K/V L2 reuse).
__global__ __launch_bounds__(512) void k_attn(
    const unsigned short* __restrict__ Qb, const unsigned short* __restrict__ Kb,
    const unsigned short* __restrict__ Vtb,
    const float* __restrict__ bias_scale_p, unsigned short* __restrict__ Ob) {
  __shared__ __align__(16) unsigned short Kbuf[3][4096];  // 24 KB
  __shared__ __align__(16) unsigned short Vbuf[3][4096];  // 24 KB
  __shared__ __align__(16) unsigned short Ps[8][16 * 64]; // 16 KB  (= 64 KB)
  // decode: bid = (hb%8) + 8*qt + 64*(hb/8); all qt of a given hb land on XCD hb%8
  const int bid = blockIdx.x;
  const int qt = (bid >> 3) & 7;
  const int hb = ((bid >> 6) << 3) | (bid & 7);
  const int h = hb & 15, b = hb >> 4;
  const int tid = threadIdx.x, l = tid & 63, wid = tid >> 6;  // wid 0..7
  const int lr = l & 15, lg = l >> 4;
  const int q0 = qt * 128;
  const float LOG2E = 1.44269504088896f;
  const float c10 = bias_scale_p[0] * 0.1f * LOG2E;
  const float k1 = 0.125f * LOG2E;
  const float fh = PRIMES_F[h] * 3.14159265358979323846f;
  const unsigned short* Vth = Vtb + (long)h * 64 * 4096 + b * 1024;
  const int xk = (lr & 7) << 4;
  const int co[2] = {(0 + lg * 16) ^ xk, (64 + lg * 16) ^ xk};
  const int scol = ((l & 7) ^ (l >> 3)) * 8;

  // staging: wave stages rows [wid*8, wid*8+8) of K and V tiles (1 g2l16 each)
  const unsigned short* kg = Kb + (long)(b * 1024 + wid * 8 + (l >> 3)) * 1024 + h * 64 + scol;
  const unsigned short* vg = Vth + (long)(wid * 8 + (l >> 3)) * 4096 + scol;
  unsigned short* kls = &Kbuf[0][0];
  unsigned short* vls = &Vbuf[0][0];
  #define STAGE_TO(BI) \
    { g2l16(kg, kls + (BI) * 4096 + wid * 512); \
      g2l16(vg, vls + (BI) * 4096 + wid * 512); \
      kg += 64 * 1024; vg += 64; }

  STAGE_TO(0);  // tile 0
  STAGE_TO(1);  // tile 1

  // Q fragments (loop-invariant): wave's 16 q-rows
  bf16x8 af[2];
  #pragma unroll
  for (int ks = 0; ks < 2; ks++)
    af[ks] = *(const bf16x8*)(
        &Qb[(long)(b * 1024 + q0 + wid * 16 + lr) * 1024 + h * 64 + ks * 32 + lg * 8]);

  // t-side sincos (rows this lane owns: q0 + wid*16 + lg*4 + r)
  float st2[4], ct2[4];
  #pragma unroll
  for (int r = 0; r < 4; r++) {
    float tt = (float)(q0 + wid * 16 + lg * 4 + r);
    float s_, c_;
    __sincosf(fh * tt * (1.f / 1024.f), &s_, &c_);
    st2[r] = c10 * s_;
    ct2[r] = c10 * c_;
  }
  // s-side sincos: init at s = nf*16 + lr, rotate by fh*64/1024 per iter
  float ss4[4], cs4[4], sd, cd;
  __sincosf(fh * (1.f / 16.f), &sd, &cd);
  #pragma unroll
  for (int nf = 0; nf < 4; nf++)
    __sincosf(fh * (float)(nf * 16 + lr) * (1.f / 1024.f), &ss4[nf], &cs4[nf]);

  f32x4 acc_o[4] = {};
  float pden[4] = {};
  int cur = 0, stg = 2;
  __syncthreads();  // drains prologue stages (0,1) + Q loads

  for (int it = 0; it < 16; ++it) {
    if (it < 15) {
      asm volatile("s_waitcnt vmcnt(2)" ::: "memory");  // stage(it) complete
    } else {
      asm volatile("s_waitcnt vmcnt(0)" ::: "memory");
    }
    __builtin_amdgcn_s_barrier();   // all waves' stage(it) visible; buf[stg] free
    __builtin_amdgcn_sched_barrier(0);
    if (it < 14) { STAGE_TO(stg); } // tile it+2 -> buf[(it+2)%3]
    const char* Kbb = (const char*)kls + cur * 8192;
    const char* Vbb = (const char*)vls + cur * 8192;
    // S = Q K^T (wave's 16 q-rows x 64 s)
    f32x4 accs[4] = {};
    #pragma unroll
    for (int ks = 0; ks < 2; ks++) {
      bf16x8 bfr[4];
      #pragma unroll
      for (int nf = 0; nf < 4; nf++)
        bfr[nf] = *(const bf16x8*)(Kbb + (nf * 16 + lr) * 128 + co[ks]);
      __builtin_amdgcn_s_setprio(1);
      #pragma unroll
      for (int nf = 0; nf < 4; nf++)
        accs[nf] = __builtin_amdgcn_mfma_f32_16x16x32_bf16(af[ks], bfr[nf], accs[nf], 0, 0, 0);
      __builtin_amdgcn_s_setprio(0);
    }
    // P = exp2(S*k1 + st2*cos_s - ct2*sin_s); partials; P -> LDS (swizzled bf16)
    char* Pw = (char*)&Ps[wid][0];
    #pragma unroll
    for (int nf = 0; nf < 4; nf++) {
      #pragma unroll
      for (int r = 0; r < 4; r++) {
        float v = fmaf(accs[nf][r], k1, fmaf(st2[r], cs4[nf], -ct2[r] * ss4[nf]));
        float p;
        asm("v_exp_f32 %0, %1" : "=v"(p) : "v"(v));
        pden[r] += p;
        union { float f; unsigned int u; } pu; pu.f = p;
        const int prow = lg * 4 + r;
        *(unsigned short*)(Pw + prow * 128 + ((nf * 32 + lr * 2) ^ ((prow & 7) << 4))) =
            (unsigned short)((pu.u + 0x8000u) >> 16);
      }
    }
    // O += P @ V
    #pragma unroll
    for (int ks = 0; ks < 2; ks++) {
      bf16x8 pa = *(const bf16x8*)(Pw + lr * 128 + co[ks]);
      bf16x8 vb[4];
      #pragma unroll
      for (int nf = 0; nf < 4; nf++)
        vb[nf] = *(const bf16x8*)(Vbb + (nf * 16 + lr) * 128 + co[ks]);
      __builtin_amdgcn_s_setprio(1);
      #pragma unroll
      for (int nf = 0; nf < 4; nf++)
        acc_o[nf] = __builtin_amdgcn_mfma_f32_16x16x32_bf16(pa, vb[nf], acc_o[nf], 0, 0, 0);
      __builtin_amdgcn_s_setprio(0);
    }
    // rotate s-side sincos (s += 64) and buffer indices
    #pragma unroll
    for (int nf = 0; nf < 4; nf++) {
      float c_ = cs4[nf] * cd - ss4[nf] * sd;
      ss4[nf] = ss4[nf] * cd + cs4[nf] * sd;
      cs4[nf] = c_;
    }
    cur = (cur == 2) ? 0 : cur + 1;
    stg = (stg == 2) ? 0 : stg + 1;
  }
  #undef STAGE_TO
  // finish den: reduce across the 16 lanes of each row-group
  #pragma unroll
  for (int r = 0; r < 4; r++) {
    float dsum = pden[r];
    #pragma unroll
    for (int off = 1; off < 16; off <<= 1) dsum += __shfl_xor(dsum, off, 64);
    pden[r] = 1.0f / dsum;
  }
  const int tg = q0 + wid * 16 + lg * 4;
  #pragma unroll
  for (int nf = 0; nf < 4; nf++) {
    const int dd = nf * 16 + lr;
    #pragma unroll
    for (int r = 0; r < 4; r++) {
      float val = acc_o[nf][r] * pden[r];
      Ob[(long)(b * 1024 + tg + r) * 1024 + h * 64 + dd] = f2bf(val);
    }
  }
}

extern "C" void kernel_launch(void* const* d_in, const int* in_sizes, int n_in,
                              void* d_out, int out_size, void* d_ws, size_t ws_size,
                              hipStream_t stream) {
  const float* x   = (const float*)d_in[0];
  const float* Wq  = (const float*)d_in[1];
  const float* bq  = (const float*)d_in[2];
  const float* Wk  = (const float*)d_in[3];
  const float* bk  = (const float*)d_in[4];
  const float* Wv  = (const float*)d_in[5];
  const float* bv  = (const float*)d_in[6];
  const float* Wo  = (const float*)d_in[7];
  const float* bo  = (const float*)d_in[8];
  const float* bsc = (const float*)d_in[10];
  const float* alp = (const float*)d_in[11];
  char* ws = (char*)d_ws;
  unsigned short* Gm  = (unsigned short*)(ws + OFF_GMAT);
  unsigned short* xb  = (unsigned short*)(ws + OFF_XB);
  unsigned short* xbT = (unsigned short*)(ws + OFF_XBT);
  unsigned short* Xf  = (unsigned short*)(ws + OFF_XF);
  unsigned short* WqT = (unsigned short*)(ws + OFF_WQT);
  unsigned short* WvT = (unsigned short*)(ws + OFF_WVT);
  unsigned short* WoT = (unsigned short*)(ws + OFF_WOT);
  unsigned short* Qb  = xbT;  // alias: xbT dead after k_fv (its last reader)
  unsigned short* Kb  = (unsigned short*)(ws + OFF_KB);
  unsigned short* Vtb = (unsigned short*)(ws + OFF_VTB);
  unsigned short* Ob  = Xf;   // alias: Xf dead after QK projection

  // prep: x cast+transpose, 4 weight transposes, Gm via closed-form g (z=8)
  k_prep<<<dim3(32, 32, 9), 256, 0, stream>>>(x, Wq, Wk, Wv, Wo, alp, xb, xbT, WqT, Gm);
  // V^T = Wv^T X^T + bv (bid<256, 16kt) + X' = G @ X banded +-64 (bid>=256, 4kt)
  k_fv<<<512, 256, 0, stream>>>(Gm, xbT, WvT, xb, bv, Xf, Vtb);
  // Q = X' Wq + bq and K = X' Wk + bk, fused (WqT/WkT contiguous)
  k_gemm5<<<512, 256, 0, stream>>>(Xf, WqT, bq, bk, Qb, Kb);
  k_attn<<<512, 512, 0, stream>>>(Qb, Kb, Vtb, bsc, Ob);
  // out = O Wo + bo (fp32)
  k_gemmO<<<512, 256, 0, stream>>>(Ob, WoT, bo, (float*)d_out);
}